// Round 4
// baseline (9873.853 us; speedup 1.0000x reference)
//
#include <hip/hip_runtime.h>
#include <hip/hip_bf16.h>
#include <math.h>

typedef __hip_bfloat16 bf16;

#define TT 4
#define CCH 256
#define HGT 120
#define WID 216
#define HWP (HGT*WID)   // 25920
#define NBT 8

__device__ __forceinline__ float bfu2f(unsigned short u) {
    union { unsigned int i; float f; } c; c.i = ((unsigned int)u) << 16; return c.f;
}
__device__ __forceinline__ float bflo2f(unsigned int u) {
    union { unsigned int i; float f; } c; c.i = u << 16; return c.f;
}
__device__ __forceinline__ float bfhi2f(unsigned int u) {
    union { unsigned int i; float f; } c; c.i = u & 0xffff0000u; return c.f;
}

// ---------------- QKV projection + patchify write (one 64-ch slice) -------------
// grid (405, 8), block 256. Block: 64 pixels of one image; outputs q,k,v slice.
__global__ __launch_bounds__(256)
void qkv_patch_kernel(const float* __restrict__ x,
                      const float* __restrict__ Wq, const float* __restrict__ bq,
                      const float* __restrict__ Wk, const float* __restrict__ bk,
                      const float* __restrict__ Wv, const float* __restrict__ bv,
                      bf16* __restrict__ Qp, bf16* __restrict__ Kp, bf16* __restrict__ Vp,
                      int c0, int oh, int ow, int ph, int pw, int N, int D)
{
    __shared__ float xs[32][64];        // [c][px]
    __shared__ float wts[3][32][68];    // [kind][c][och], padded
    const int tid = threadIdx.x;
    const int bt = blockIdx.y;
    const int p0 = blockIdx.x * 64;
    const int b = bt / TT, t = bt % TT;
    const int px4 = tid & 15, og = tid >> 4;   // 4 pixels x 4 och micro-tile

    float acc[3][4][4];
    #pragma unroll
    for (int oi = 0; oi < 4; ++oi) {
        const int och = c0 + og*4 + oi;
        const float b0 = bq[och], b1 = bk[och], b2 = bv[och];
        #pragma unroll
        for (int pi = 0; pi < 4; ++pi) { acc[0][oi][pi]=b0; acc[1][oi][pi]=b1; acc[2][oi][pi]=b2; }
    }

    for (int cb = 0; cb < CCH; cb += 32) {
        __syncthreads();
        #pragma unroll
        for (int i = 0; i < 8; ++i) {               // stage x: 32c x 64px
            int idx = tid + i*256;
            int c = idx >> 6, j = idx & 63;
            xs[c][j] = x[((size_t)bt*CCH + cb + c)*HWP + p0 + j];
        }
        #pragma unroll
        for (int i = 0; i < 8; ++i) {               // stage weights: 64och x 32c, transposed
            int idx = tid + i*256;
            int och = idx >> 5, cc = idx & 31;
            size_t wi = (size_t)(c0+och)*CCH + cb + cc;
            wts[0][cc][och] = Wq[wi];
            wts[1][cc][och] = Wk[wi];
            wts[2][cc][och] = Wv[wi];
        }
        __syncthreads();
        #pragma unroll 4
        for (int c = 0; c < 32; ++c) {
            float4 xv4 = *(const float4*)&xs[c][px4*4];
            float xv[4] = {xv4.x, xv4.y, xv4.z, xv4.w};
            #pragma unroll
            for (int kind = 0; kind < 3; ++kind) {
                float4 wv4 = *(const float4*)&wts[kind][c][og*4];
                float wv[4] = {wv4.x, wv4.y, wv4.z, wv4.w};
                #pragma unroll
                for (int oi = 0; oi < 4; ++oi)
                    #pragma unroll
                    for (int pi = 0; pi < 4; ++pi)
                        acc[kind][oi][pi] += wv[oi]*xv[pi];
            }
        }
    }

    const int phpw = ph*pw;
    #pragma unroll
    for (int pi = 0; pi < 4; ++pi) {
        int p = p0 + px4*4 + pi;
        int h = p / WID, w = p % WID;
        int ohi = h / ph, py = h % ph;
        int owi = w / pw, pxx = w % pw;
        int n = (t*oh + ohi)*ow + owi;
        size_t base = ((size_t)b*N + n)*D + py*pw + pxx;
        #pragma unroll
        for (int oi = 0; oi < 4; ++oi) {
            size_t a = base + (size_t)(og*4 + oi)*phpw;
            Qp[a] = __float2bfloat16(acc[0][oi][pi]);
            Kp[a] = __float2bfloat16(acc[1][oi][pi]);
            Vp[a] = __float2bfloat16(acc[2][oi][pi]);
        }
    }
}

// ---------------- per-patch mask means -------------
__global__ __launch_bounds__(256)
void mask_kernel(const float* __restrict__ m, float* __restrict__ maskf,
                 int oh, int ow, int ph, int pw, int N)
{
    const int bn = blockIdx.x;
    const int b = bn / N, n = bn % N;
    const int ohow = oh*ow;
    const int t = n / ohow, r = n % ohow;
    const int ohi = r / ow, owi = r % ow;
    const float* mp = m + (size_t)(b*TT + t)*HWP;
    const int cnt = ph*pw;
    double s = 0.0;
    for (int i = threadIdx.x; i < cnt; i += 256) {
        int py = i / pw, px = i % pw;
        s += (double)mp[(size_t)(ohi*ph + py)*WID + owi*pw + px];
    }
    __shared__ double red[4];
    #pragma unroll
    for (int off = 32; off > 0; off >>= 1) s += __shfl_down(s, off);
    if ((threadIdx.x & 63) == 0) red[threadIdx.x >> 6] = s;
    __syncthreads();
    if (threadIdx.x == 0) {
        double tot = red[0]+red[1]+red[2]+red[3];
        maskf[bn] = (tot > 0.5*(double)cnt) ? 1.0f : 0.0f;
    }
}

__global__ void zero_kernel(float* __restrict__ p, int n) {
    int i = blockIdx.x*256 + threadIdx.x;
    if (i < n) p[i] = 0.f;
}

// ---------------- scores = Qp·Kp^T (split-K, fp32 atomic accumulate) -------------
// grid (N/64, N/64, 2*nsplit), block 256 (16x16 threads, 4x4 micro)
__global__ __launch_bounds__(256)
void scores_kernel(const bf16* __restrict__ Qp, const bf16* __restrict__ Kp,
                   float* __restrict__ S, int N, int D, int nsplit)
{
    const int tid = threadIdx.x;
    const int b = blockIdx.z / nsplit, sp = blockIdx.z % nsplit;
    const int kchunks = D >> 5;
    const int per = (kchunks + nsplit - 1)/nsplit;
    const int k0 = sp*per*32;
    const int k1 = min(D, k0 + per*32);
    const bf16* Qb = Qp + (size_t)b*N*D;
    const bf16* Kb = Kp + (size_t)b*N*D;
    const int n0 = blockIdx.y*64, m0 = blockIdx.x*64;
    __shared__ float as[32][68], bs[32][68];   // [k][row], padded
    const int tx = tid & 15, ty = tid >> 4;
    const int row = tid >> 2, kg = tid & 3;
    float acc[4][4] = {};
    for (int kb = k0; kb < k1; kb += 32) {
        __syncthreads();
        {
            const uint4 ra = *(const uint4*)(Qb + (size_t)(n0+row)*D + kb + kg*8);
            as[kg*8+0][row]=bflo2f(ra.x); as[kg*8+1][row]=bfhi2f(ra.x);
            as[kg*8+2][row]=bflo2f(ra.y); as[kg*8+3][row]=bfhi2f(ra.y);
            as[kg*8+4][row]=bflo2f(ra.z); as[kg*8+5][row]=bfhi2f(ra.z);
            as[kg*8+6][row]=bflo2f(ra.w); as[kg*8+7][row]=bfhi2f(ra.w);
            const uint4 rb = *(const uint4*)(Kb + (size_t)(m0+row)*D + kb + kg*8);
            bs[kg*8+0][row]=bflo2f(rb.x); bs[kg*8+1][row]=bfhi2f(rb.x);
            bs[kg*8+2][row]=bflo2f(rb.y); bs[kg*8+3][row]=bfhi2f(rb.y);
            bs[kg*8+4][row]=bflo2f(rb.z); bs[kg*8+5][row]=bfhi2f(rb.z);
            bs[kg*8+6][row]=bflo2f(rb.w); bs[kg*8+7][row]=bfhi2f(rb.w);
        }
        __syncthreads();
        #pragma unroll
        for (int kk = 0; kk < 32; ++kk) {
            float4 a4 = *(const float4*)&as[kk][ty*4];
            float4 b4 = *(const float4*)&bs[kk][tx*4];
            float av[4]={a4.x,a4.y,a4.z,a4.w}, bv[4]={b4.x,b4.y,b4.z,b4.w};
            #pragma unroll
            for (int i=0;i<4;++i)
                #pragma unroll
                for (int j=0;j<4;++j) acc[i][j] += av[i]*bv[j];
        }
    }
    #pragma unroll
    for (int i=0;i<4;++i) {
        size_t roff = ((size_t)b*N + n0 + ty*4 + i)*N + m0 + tx*4;
        #pragma unroll
        for (int j=0;j<4;++j) atomicAdd(&S[roff + j], acc[i][j]);
    }
}

// ---------------- masked softmax (in place, applies 1/sqrt(D) and mask) -------------
__global__ __launch_bounds__(256)
void softmax_kernel(float* __restrict__ S, const float* __restrict__ maskf,
                    int N, float rscale)
{
    __shared__ float buf[2304];
    __shared__ float red[4];
    __shared__ float bval;
    const int tid = threadIdx.x;
    const int bn = blockIdx.x;
    const int b = bn / N;
    float* rowp = S + (size_t)bn*N;
    const float* mk = maskf + (size_t)b*N;
    float mx = -3.0e38f;
    for (int mc = tid; mc < N; mc += 256) {
        float s = rowp[mc]*rscale;
        if (mk[mc] > 0.5f) s = -1e9f;
        buf[mc] = s;
        mx = fmaxf(mx, s);
    }
    #pragma unroll
    for (int off = 32; off > 0; off >>= 1) mx = fmaxf(mx, __shfl_down(mx, off));
    if ((tid & 63) == 0) red[tid >> 6] = mx;
    __syncthreads();
    if (tid == 0) bval = fmaxf(fmaxf(red[0],red[1]), fmaxf(red[2],red[3]));
    __syncthreads();
    const float rm = bval;
    float sum = 0.f;
    for (int mc = tid; mc < N; mc += 256) {
        float e = __expf(buf[mc]-rm);
        buf[mc] = e; sum += e;
    }
    #pragma unroll
    for (int off = 32; off > 0; off >>= 1) sum += __shfl_down(sum, off);
    if ((tid & 63) == 0) red[tid >> 6] = sum;
    __syncthreads();
    if (tid == 0) bval = 1.0f/(red[0]+red[1]+red[2]+red[3]);
    __syncthreads();
    const float inv = bval;
    for (int mc = tid; mc < N; mc += 256) rowp[mc] = buf[mc]*inv;
}

// ---------------- yi = P·Vp, un-patchify scatter into y (bf16) -------------
// grid (D/64, N/64, 2), block 256
__global__ __launch_bounds__(256)
void pv_kernel(const float* __restrict__ P, const bf16* __restrict__ Vp,
               bf16* __restrict__ y, int N, int D,
               int c0, int oh, int ow, int ph, int pw)
{
    const int tid = threadIdx.x;
    const int b = blockIdx.z;
    const float* Pb = P + (size_t)b*N*N;
    const bf16* Vb = Vp + (size_t)b*N*D;
    const int n0 = blockIdx.y*64, d0 = blockIdx.x*64;
    __shared__ float ps[32][68];   // [m][n], padded
    __shared__ float vs[32][64];   // [m][d]
    const int tx = tid & 15, ty = tid >> 4;
    const int prow = tid >> 2, pkg = tid & 3;
    const int vrow = tid >> 3, vdg = tid & 7;
    float acc[4][4] = {};
    for (int mb = 0; mb < N; mb += 32) {
        __syncthreads();
        {
            const float* src = Pb + (size_t)(n0+prow)*N + mb + pkg*8;
            float4 a = *(const float4*)src;
            float4 c = *(const float4*)(src+4);
            ps[pkg*8+0][prow]=a.x; ps[pkg*8+1][prow]=a.y; ps[pkg*8+2][prow]=a.z; ps[pkg*8+3][prow]=a.w;
            ps[pkg*8+4][prow]=c.x; ps[pkg*8+5][prow]=c.y; ps[pkg*8+6][prow]=c.z; ps[pkg*8+7][prow]=c.w;
            const uint4 rv = *(const uint4*)(Vb + (size_t)(mb+vrow)*D + d0 + vdg*8);
            vs[vrow][vdg*8+0]=bflo2f(rv.x); vs[vrow][vdg*8+1]=bfhi2f(rv.x);
            vs[vrow][vdg*8+2]=bflo2f(rv.y); vs[vrow][vdg*8+3]=bfhi2f(rv.y);
            vs[vrow][vdg*8+4]=bflo2f(rv.z); vs[vrow][vdg*8+5]=bfhi2f(rv.z);
            vs[vrow][vdg*8+6]=bflo2f(rv.w); vs[vrow][vdg*8+7]=bfhi2f(rv.w);
        }
        __syncthreads();
        #pragma unroll
        for (int mm = 0; mm < 32; ++mm) {
            float4 a4 = *(const float4*)&ps[mm][ty*4];
            float4 b4 = *(const float4*)&vs[mm][tx*4];
            float av[4]={a4.x,a4.y,a4.z,a4.w}, bv[4]={b4.x,b4.y,b4.z,b4.w};
            #pragma unroll
            for (int i=0;i<4;++i)
                #pragma unroll
                for (int j=0;j<4;++j) acc[i][j] += av[i]*bv[j];
        }
    }
    const int ohow = oh*ow, phpw = ph*pw;
    #pragma unroll
    for (int i=0;i<4;++i) {
        int n = n0 + ty*4 + i;
        int t = n/ohow; int r = n%ohow;
        int ohi = r/ow, owi = r%ow;
        size_t ybase = ((size_t)(b*TT+t)*CCH + c0)*HWP;
        int hb = ohi*ph, wb = owi*pw;
        #pragma unroll
        for (int j=0;j<4;++j) {
            int d = d0 + tx*4 + j;
            int ck = d/phpw; int r2 = d%phpw;
            int py = r2/pw, pxx = r2%pw;
            y[ybase + (size_t)ck*HWP + (size_t)(hb+py)*WID + wb + pxx] = __float2bfloat16(acc[i][j]);
        }
    }
}

// ---------------- 3x3 conv + bias + LeakyReLU -------------
// grid (7, 15, 8*16), block 256. Tile: 32w x 8h pixels, 16 out channels.
__global__ __launch_bounds__(256)
void conv_kernel(const bf16* __restrict__ y, const float* __restrict__ Wo,
                 const float* __restrict__ bo, float* __restrict__ out)
{
    const int tid = threadIdx.x;
    const int z = blockIdx.z;
    const int bt = z >> 4, o0 = (z & 15) * 16;
    const int w0 = blockIdx.x * 32, h0 = blockIdx.y * 8;
    const int pxx = tid & 31, pyy = tid >> 5;
    __shared__ float ys[16][10][34];
    __shared__ float ws[16][9][16];   // [c][k][o]
    float acc[16];
    #pragma unroll
    for (int oo=0;oo<16;++oo) acc[oo] = bo[o0+oo];
    const unsigned short* yu = (const unsigned short*)y;
    for (int cb = 0; cb < CCH; cb += 16) {
        __syncthreads();
        for (int i = tid; i < 16*340; i += 256) {
            int c = i / 340, r = i % 340;
            int yy = r / 34, xx = r % 34;
            int gh = h0 - 1 + yy, gw = w0 - 1 + xx;
            float v = 0.f;
            if (gh >= 0 && gh < HGT && gw >= 0 && gw < WID)
                v = bfu2f(yu[((size_t)bt*CCH + cb + c)*HWP + (size_t)gh*WID + gw]);
            ys[c][yy][xx] = v;
        }
        for (int i = tid; i < 2304; i += 256) {
            int oo = i / 144, r = i % 144;
            int cc = r / 9, k = r % 9;
            ws[cc][k][oo] = Wo[((size_t)(o0+oo)*CCH + cb + cc)*9 + k];
        }
        __syncthreads();
        #pragma unroll 2
        for (int c = 0; c < 16; ++c) {
            #pragma unroll
            for (int ky = 0; ky < 3; ++ky) {
                #pragma unroll
                for (int kx = 0; kx < 3; ++kx) {
                    float v = ys[c][pyy+ky][pxx+kx];
                    #pragma unroll
                    for (int o4 = 0; o4 < 4; ++o4) {
                        float4 w4 = *(const float4*)&ws[c][ky*3+kx][o4*4];
                        acc[o4*4+0] += v*w4.x;
                        acc[o4*4+1] += v*w4.y;
                        acc[o4*4+2] += v*w4.z;
                        acc[o4*4+3] += v*w4.w;
                    }
                }
            }
        }
    }
    const int gw = w0 + pxx, gh = h0 + pyy;
    if (gw < WID) {
        size_t base = ((size_t)bt*CCH + o0)*HWP + (size_t)gh*WID + gw;
        #pragma unroll
        for (int oo=0;oo<16;++oo) {
            float r = acc[oo];
            out[base + (size_t)oo*HWP] = (r >= 0.f) ? r : 0.2f*r;
        }
    }
}

extern "C" void kernel_launch(void* const* d_in, const int* in_sizes, int n_in,
                              void* d_out, int out_size, void* d_ws, size_t ws_size,
                              hipStream_t stream)
{
    const float* x  = (const float*)d_in[0];
    const float* m  = (const float*)d_in[1];
    const float* Wq = (const float*)d_in[2];
    const float* bq = (const float*)d_in[3];
    const float* Wk = (const float*)d_in[4];
    const float* bk = (const float*)d_in[5];
    const float* Wv = (const float*)d_in[6];
    const float* bv = (const float*)d_in[7];
    const float* Wo = (const float*)d_in[8];
    const float* bo = (const float*)d_in[9];
    float* out = (float*)d_out;

    char* ws = (char*)d_ws;
    bf16*  Qp = (bf16*) (ws + 0);            // 13,271,040 bf16
    bf16*  Kp = (bf16*) (ws + 26542080);
    bf16*  Vp = (bf16*) (ws + 53084160);
    float* S  = (float*)(ws + 79626240);     // up to 2*2304*2304 fp32
    bf16*  Y  = (bf16*) (ws + 122093568);    // 53,084,160 bf16
    float* MK = (float*)(ws + 228261888);    // 4608 fp32

    static const int s_pw[4] = {54,27,18,9};
    static const int s_ph[4] = {30,15,10,5};
    static const int s_oo[4] = {4,8,12,24};   // oh == ow per scale
    static const int s_N[4]  = {64,256,576,2304};
    static const int s_D[4]  = {103680,25920,11520,2880};
    static const int s_sp[4] = {256,64,16,1};

    for (int s = 0; s < 4; ++s) {
        const int pw = s_pw[s], ph = s_ph[s], oo = s_oo[s];
        const int N = s_N[s], D = s_D[s], nsplit = s_sp[s];
        const int c0 = s*64;
        qkv_patch_kernel<<<dim3(405, NBT), 256, 0, stream>>>(
            x, Wq, bq, Wk, bk, Wv, bv, Qp, Kp, Vp, c0, oo, oo, ph, pw, N, D);
        mask_kernel<<<dim3(2*N), 256, 0, stream>>>(m, MK, oo, oo, ph, pw, N);
        const int ztot = 2*N*N;
        zero_kernel<<<dim3((ztot+255)/256), 256, 0, stream>>>(S, ztot);
        scores_kernel<<<dim3(N/64, N/64, 2*nsplit), 256, 0, stream>>>(Qp, Kp, S, N, D, nsplit);
        softmax_kernel<<<dim3(2*N), 256, 0, stream>>>(S, MK, N, 1.0f/sqrtf((float)D));
        pv_kernel<<<dim3(D/64, N/64, 2), 256, 0, stream>>>(S, Vp, Y, N, D, c0, oo, oo, ph, pw);
    }
    conv_kernel<<<dim3(7, 15, NBT*16), 256, 0, stream>>>(Y, Wo, bo, out);
}

// Round 6
// 6110.934 us; speedup vs baseline: 1.6158x; 1.6158x over previous
//
#include <hip/hip_runtime.h>
#include <hip/hip_bf16.h>
#include <math.h>

typedef __hip_bfloat16 bf16;
typedef __attribute__((ext_vector_type(8))) short short8v;
typedef __attribute__((ext_vector_type(4))) float floatx4;

#define TT 4
#define CCH 256
#define HGT 120
#define WID 216
#define HWP (HGT*WID)   // 25920
#define NBT 8

__device__ __forceinline__ float bfu2f(unsigned short u) {
    union { unsigned int i; float f; } c; c.i = ((unsigned int)u) << 16; return c.f;
}
__device__ __forceinline__ float bflo2f(unsigned int u) {
    union { unsigned int i; float f; } c; c.i = u << 16; return c.f;
}
__device__ __forceinline__ float bfhi2f(unsigned int u) {
    union { unsigned int i; float f; } c; c.i = u & 0xffff0000u; return c.f;
}
__device__ __forceinline__ short8v lds_load8(const unsigned short* p) {
    short8v r;
    *(uint2*)&r       = *(const uint2*)p;
    *((uint2*)&r + 1) = *(const uint2*)(p + 4);
    return r;
}

// ---------------- QKV projection + patchify write (one 64-ch slice) -------------
// grid (405, 8), block 256. Block: 64 pixels of one image; outputs q,k,v slice.
__global__ __launch_bounds__(256)
void qkv_patch_kernel(const float* __restrict__ x,
                      const float* __restrict__ Wq, const float* __restrict__ bq,
                      const float* __restrict__ Wk, const float* __restrict__ bk,
                      const float* __restrict__ Wv, const float* __restrict__ bv,
                      bf16* __restrict__ Qp, bf16* __restrict__ Kp, bf16* __restrict__ Vp,
                      int c0, int oh, int ow, int ph, int pw, int N, int D)
{
    __shared__ float xs[32][64];        // [c][px]
    __shared__ float wts[3][32][68];    // [kind][c][och], padded
    const int tid = threadIdx.x;
    const int bt = blockIdx.y;
    const int p0 = blockIdx.x * 64;
    const int b = bt / TT, t = bt % TT;
    const int px4 = tid & 15, og = tid >> 4;   // 4 pixels x 4 och micro-tile

    float acc[3][4][4];
    #pragma unroll
    for (int oi = 0; oi < 4; ++oi) {
        const int och = c0 + og*4 + oi;
        const float b0 = bq[och], b1 = bk[och], b2 = bv[och];
        #pragma unroll
        for (int pi = 0; pi < 4; ++pi) { acc[0][oi][pi]=b0; acc[1][oi][pi]=b1; acc[2][oi][pi]=b2; }
    }

    for (int cb = 0; cb < CCH; cb += 32) {
        __syncthreads();
        #pragma unroll
        for (int i = 0; i < 8; ++i) {               // stage x: 32c x 64px
            int idx = tid + i*256;
            int c = idx >> 6, j = idx & 63;
            xs[c][j] = x[((size_t)bt*CCH + cb + c)*HWP + p0 + j];
        }
        #pragma unroll
        for (int i = 0; i < 8; ++i) {               // stage weights: 64och x 32c, transposed
            int idx = tid + i*256;
            int och = idx >> 5, cc = idx & 31;
            size_t wi = (size_t)(c0+och)*CCH + cb + cc;
            wts[0][cc][och] = Wq[wi];
            wts[1][cc][och] = Wk[wi];
            wts[2][cc][och] = Wv[wi];
        }
        __syncthreads();
        #pragma unroll 4
        for (int c = 0; c < 32; ++c) {
            float4 xv4 = *(const float4*)&xs[c][px4*4];
            float xv[4] = {xv4.x, xv4.y, xv4.z, xv4.w};
            #pragma unroll
            for (int kind = 0; kind < 3; ++kind) {
                float4 wv4 = *(const float4*)&wts[kind][c][og*4];
                float wv[4] = {wv4.x, wv4.y, wv4.z, wv4.w};
                #pragma unroll
                for (int oi = 0; oi < 4; ++oi)
                    #pragma unroll
                    for (int pi = 0; pi < 4; ++pi)
                        acc[kind][oi][pi] += wv[oi]*xv[pi];
            }
        }
    }

    const int phpw = ph*pw;
    #pragma unroll
    for (int pi = 0; pi < 4; ++pi) {
        int p = p0 + px4*4 + pi;
        int h = p / WID, w = p % WID;
        int ohi = h / ph, py = h % ph;
        int owi = w / pw, pxx = w % pw;
        int n = (t*oh + ohi)*ow + owi;
        size_t base = ((size_t)b*N + n)*D + py*pw + pxx;
        #pragma unroll
        for (int oi = 0; oi < 4; ++oi) {
            size_t a = base + (size_t)(og*4 + oi)*phpw;
            Qp[a] = __float2bfloat16(acc[0][oi][pi]);
            Kp[a] = __float2bfloat16(acc[1][oi][pi]);
            Vp[a] = __float2bfloat16(acc[2][oi][pi]);
        }
    }
}

// ---------------- per-patch mask means -------------
__global__ __launch_bounds__(256)
void mask_kernel(const float* __restrict__ m, float* __restrict__ maskf,
                 int oh, int ow, int ph, int pw, int N)
{
    const int bn = blockIdx.x;
    const int b = bn / N, n = bn % N;
    const int ohow = oh*ow;
    const int t = n / ohow, r = n % ohow;
    const int ohi = r / ow, owi = r % ow;
    const float* mp = m + (size_t)(b*TT + t)*HWP;
    const int cnt = ph*pw;
    double s = 0.0;
    for (int i = threadIdx.x; i < cnt; i += 256) {
        int py = i / pw, px = i % pw;
        s += (double)mp[(size_t)(ohi*ph + py)*WID + owi*pw + px];
    }
    __shared__ double red[4];
    #pragma unroll
    for (int off = 32; off > 0; off >>= 1) s += __shfl_down(s, off);
    if ((threadIdx.x & 63) == 0) red[threadIdx.x >> 6] = s;
    __syncthreads();
    if (threadIdx.x == 0) {
        double tot = red[0]+red[1]+red[2]+red[3];
        maskf[bn] = (tot > 0.5*(double)cnt) ? 1.0f : 0.0f;
    }
}

__global__ void zero_kernel(float* __restrict__ p, int n) {
    int i = blockIdx.x*256 + threadIdx.x;
    if (i < n) p[i] = 0.f;
}

// ---------------- scores = Qp·Kp^T (split-K, fp32 atomic accumulate) -------------
// grid (N/64, N/64, 2*nsplit), block 256 (16x16 threads, 4x4 micro)
__global__ __launch_bounds__(256)
void scores_kernel(const bf16* __restrict__ Qp, const bf16* __restrict__ Kp,
                   float* __restrict__ S, int N, int D, int nsplit)
{
    const int tid = threadIdx.x;
    const int b = blockIdx.z / nsplit, sp = blockIdx.z % nsplit;
    const int kchunks = D >> 5;
    const int per = (kchunks + nsplit - 1)/nsplit;
    const int k0 = sp*per*32;
    const int k1 = min(D, k0 + per*32);
    const bf16* Qb = Qp + (size_t)b*N*D;
    const bf16* Kb = Kp + (size_t)b*N*D;
    const int n0 = blockIdx.y*64, m0 = blockIdx.x*64;
    __shared__ float as[32][68], bs[32][68];   // [k][row], padded
    const int tx = tid & 15, ty = tid >> 4;
    const int row = tid >> 2, kg = tid & 3;
    float acc[4][4] = {};
    for (int kb = k0; kb < k1; kb += 32) {
        __syncthreads();
        {
            const uint4 ra = *(const uint4*)(Qb + (size_t)(n0+row)*D + kb + kg*8);
            as[kg*8+0][row]=bflo2f(ra.x); as[kg*8+1][row]=bfhi2f(ra.x);
            as[kg*8+2][row]=bflo2f(ra.y); as[kg*8+3][row]=bfhi2f(ra.y);
            as[kg*8+4][row]=bflo2f(ra.z); as[kg*8+5][row]=bfhi2f(ra.z);
            as[kg*8+6][row]=bflo2f(ra.w); as[kg*8+7][row]=bfhi2f(ra.w);
            const uint4 rb = *(const uint4*)(Kb + (size_t)(m0+row)*D + kb + kg*8);
            bs[kg*8+0][row]=bflo2f(rb.x); bs[kg*8+1][row]=bfhi2f(rb.x);
            bs[kg*8+2][row]=bflo2f(rb.y); bs[kg*8+3][row]=bfhi2f(rb.y);
            bs[kg*8+4][row]=bflo2f(rb.z); bs[kg*8+5][row]=bfhi2f(rb.z);
            bs[kg*8+6][row]=bflo2f(rb.w); bs[kg*8+7][row]=bfhi2f(rb.w);
        }
        __syncthreads();
        #pragma unroll
        for (int kk = 0; kk < 32; ++kk) {
            float4 a4 = *(const float4*)&as[kk][ty*4];
            float4 b4 = *(const float4*)&bs[kk][tx*4];
            float av[4]={a4.x,a4.y,a4.z,a4.w}, bv[4]={b4.x,b4.y,b4.z,b4.w};
            #pragma unroll
            for (int i=0;i<4;++i)
                #pragma unroll
                for (int j=0;j<4;++j) acc[i][j] += av[i]*bv[j];
        }
    }
    #pragma unroll
    for (int i=0;i<4;++i) {
        size_t roff = ((size_t)b*N + n0 + ty*4 + i)*N + m0 + tx*4;
        #pragma unroll
        for (int j=0;j<4;++j) atomicAdd(&S[roff + j], acc[i][j]);
    }
}

// ---------------- masked softmax (in place, applies 1/sqrt(D) and mask) -------------
__global__ __launch_bounds__(256)
void softmax_kernel(float* __restrict__ S, const float* __restrict__ maskf,
                    int N, float rscale)
{
    __shared__ float buf[2304];
    __shared__ float red[4];
    __shared__ float bval;
    const int tid = threadIdx.x;
    const int bn = blockIdx.x;
    const int b = bn / N;
    float* rowp = S + (size_t)bn*N;
    const float* mk = maskf + (size_t)b*N;
    float mx = -3.0e38f;
    for (int mc = tid; mc < N; mc += 256) {
        float s = rowp[mc]*rscale;
        if (mk[mc] > 0.5f) s = -1e9f;
        buf[mc] = s;
        mx = fmaxf(mx, s);
    }
    #pragma unroll
    for (int off = 32; off > 0; off >>= 1) mx = fmaxf(mx, __shfl_down(mx, off));
    if ((tid & 63) == 0) red[tid >> 6] = mx;
    __syncthreads();
    if (tid == 0) bval = fmaxf(fmaxf(red[0],red[1]), fmaxf(red[2],red[3]));
    __syncthreads();
    const float rm = bval;
    float sum = 0.f;
    for (int mc = tid; mc < N; mc += 256) {
        float e = __expf(buf[mc]-rm);
        buf[mc] = e; sum += e;
    }
    #pragma unroll
    for (int off = 32; off > 0; off >>= 1) sum += __shfl_down(sum, off);
    if ((tid & 63) == 0) red[tid >> 6] = sum;
    __syncthreads();
    if (tid == 0) bval = 1.0f/(red[0]+red[1]+red[2]+red[3]);
    __syncthreads();
    const float inv = bval;
    for (int mc = tid; mc < N; mc += 256) rowp[mc] = buf[mc]*inv;
}

// ---------------- yi = P·Vp, un-patchify scatter into y (bf16) -------------
// grid (D/64, N/64, 2), block 256
__global__ __launch_bounds__(256)
void pv_kernel(const float* __restrict__ P, const bf16* __restrict__ Vp,
               bf16* __restrict__ y, int N, int D,
               int c0, int oh, int ow, int ph, int pw)
{
    const int tid = threadIdx.x;
    const int b = blockIdx.z;
    const float* Pb = P + (size_t)b*N*N;
    const bf16* Vb = Vp + (size_t)b*N*D;
    const int n0 = blockIdx.y*64, d0 = blockIdx.x*64;
    __shared__ float ps[32][68];   // [m][n], padded
    __shared__ float vs[32][64];   // [m][d]
    const int tx = tid & 15, ty = tid >> 4;
    const int prow = tid >> 2, pkg = tid & 3;
    const int vrow = tid >> 3, vdg = tid & 7;
    float acc[4][4] = {};
    for (int mb = 0; mb < N; mb += 32) {
        __syncthreads();
        {
            const float* src = Pb + (size_t)(n0+prow)*N + mb + pkg*8;
            float4 a = *(const float4*)src;
            float4 c = *(const float4*)(src+4);
            ps[pkg*8+0][prow]=a.x; ps[pkg*8+1][prow]=a.y; ps[pkg*8+2][prow]=a.z; ps[pkg*8+3][prow]=a.w;
            ps[pkg*8+4][prow]=c.x; ps[pkg*8+5][prow]=c.y; ps[pkg*8+6][prow]=c.z; ps[pkg*8+7][prow]=c.w;
            const uint4 rv = *(const uint4*)(Vb + (size_t)(mb+vrow)*D + d0 + vdg*8);
            vs[vrow][vdg*8+0]=bflo2f(rv.x); vs[vrow][vdg*8+1]=bfhi2f(rv.x);
            vs[vrow][vdg*8+2]=bflo2f(rv.y); vs[vrow][vdg*8+3]=bfhi2f(rv.y);
            vs[vrow][vdg*8+4]=bflo2f(rv.z); vs[vrow][vdg*8+5]=bfhi2f(rv.z);
            vs[vrow][vdg*8+6]=bflo2f(rv.w); vs[vrow][vdg*8+7]=bfhi2f(rv.w);
        }
        __syncthreads();
        #pragma unroll
        for (int mm = 0; mm < 32; ++mm) {
            float4 a4 = *(const float4*)&ps[mm][ty*4];
            float4 b4 = *(const float4*)&vs[mm][tx*4];
            float av[4]={a4.x,a4.y,a4.z,a4.w}, bv[4]={b4.x,b4.y,b4.z,b4.w};
            #pragma unroll
            for (int i=0;i<4;++i)
                #pragma unroll
                for (int j=0;j<4;++j) acc[i][j] += av[i]*bv[j];
        }
    }
    const int ohow = oh*ow, phpw = ph*pw;
    #pragma unroll
    for (int i=0;i<4;++i) {
        int n = n0 + ty*4 + i;
        int t = n/ohow; int r = n%ohow;
        int ohi = r/ow, owi = r%ow;
        size_t ybase = ((size_t)(b*TT+t)*CCH + c0)*HWP;
        int hb = ohi*ph, wb = owi*pw;
        #pragma unroll
        for (int j=0;j<4;++j) {
            int d = d0 + tx*4 + j;
            int ck = d/phpw; int r2 = d%phpw;
            int py = r2/pw, pxx = r2%pw;
            y[ybase + (size_t)ck*HWP + (size_t)(hb+py)*WID + wb + pxx] = __float2bfloat16(acc[i][j]);
        }
    }
}

// ---------------- weight prep: Wo fp32 [o][c][3][3] -> bf16 [off][o][c] -------------
__global__ __launch_bounds__(256)
void wprep_kernel(const float* __restrict__ Wo, bf16* __restrict__ wbf)
{
    int i = blockIdx.x*256 + threadIdx.x;   // 65536 threads: o = i>>8, c = i&255
    int o = i >> 8, c = i & 255;
    const float* src = Wo + (size_t)(o*256 + c)*9;
    #pragma unroll
    for (int off = 0; off < 9; ++off)
        wbf[(size_t)(off*256 + o)*256 + c] = __float2bfloat16(src[off]);
}

// ---------------- 3x3 conv + bias + LeakyReLU via MFMA implicit GEMM -------------
// grid (14, 30, 8*4), block 256 (4 waves). Block tile: 4h x 16w pixels, 64 out ch.
// K = 256 c * 9 offsets. Wave tile: 32 px x 32 o (2x2 MFMA 16x16x32 frags).
__global__ __launch_bounds__(256)
void conv_mfma_kernel(const bf16* __restrict__ y, const bf16* __restrict__ wbf,
                      const float* __restrict__ bo, float* __restrict__ out)
{
    __shared__ unsigned short ys[108*36];    // [pos=ry*18+rx][c], 72B rows
    __shared__ unsigned short wl[9*64*36];   // [off][o][c], 72B rows
    const int tid = threadIdx.x;
    const int bz = blockIdx.z;
    const int bt = bz >> 2, o0 = (bz & 3) * 64;
    const int w0 = blockIdx.x * 16, h0 = blockIdx.y * 4;
    const int lane = tid & 63, wv = tid >> 6;
    const int col = lane & 15, kg = lane >> 4;
    const int phalf = wv & 1, ohalf = wv >> 1;

    floatx4 acc[2][2];
    #pragma unroll
    for (int pg = 0; pg < 2; ++pg)
        #pragma unroll
        for (int og = 0; og < 2; ++og)
            acc[pg][og] = (floatx4){0.f, 0.f, 0.f, 0.f};

    const unsigned short* yu = (const unsigned short*)y;
    const unsigned short* wu = (const unsigned short*)wbf;
    const int so = tid >> 2, scg = tid & 3;      // W staging: 64 o x 4 c-groups

    for (int cb = 0; cb < CCH; cb += 32) {
        __syncthreads();
        // stage y halo: 108 pos x 32 c -> ys[pos][c]
        for (int i = tid; i < 3456; i += 256) {
            int c = i / 108, pos = i - c*108;
            int ry = pos / 18, rx = pos - ry*18;
            int gh = h0 - 1 + ry, gw = w0 - 1 + rx;
            unsigned short v = 0;
            if (gh >= 0 && gh < HGT && gw >= 0 && gw < WID)
                v = yu[((size_t)bt*CCH + cb + c)*HWP + (size_t)gh*WID + gw];
            ys[pos*36 + c] = v;
        }
        // stage W: 9 offs x 64 o x 32 c -> wl[off][o][c]
        #pragma unroll
        for (int off = 0; off < 9; ++off) {
            uint4 w4 = *(const uint4*)(wu + ((size_t)(off*256 + o0 + so)*256 + cb + scg*8));
            uint2* dst = (uint2*)&wl[off*2304 + so*36 + scg*8];
            dst[0] = make_uint2(w4.x, w4.y);
            dst[1] = make_uint2(w4.z, w4.w);
        }
        __syncthreads();
        // MFMA: D[o][px] += W[o][c] * y[c][px] per offset
        #pragma unroll
        for (int off = 0; off < 9; ++off) {
            const int ky = off / 3, kx = off - ky*3;
            short8v aw[2], by[2];
            #pragma unroll
            for (int og = 0; og < 2; ++og)
                aw[og] = lds_load8(&wl[off*2304 + (ohalf*32 + og*16 + col)*36 + kg*8]);
            #pragma unroll
            for (int pg = 0; pg < 2; ++pg) {
                const int py = phalf*2 + pg;
                by[pg] = lds_load8(&ys[((py + ky)*18 + col + kx)*36 + kg*8]);
            }
            #pragma unroll
            for (int pg = 0; pg < 2; ++pg)
                #pragma unroll
                for (int og = 0; og < 2; ++og)
                    acc[pg][og] = __builtin_amdgcn_mfma_f32_16x16x32_bf16(
                        aw[og], by[pg], acc[pg][og], 0, 0, 0);
        }
    }

    // epilogue: D col = pixel (lane&15), row = o-within-16 (kg*4+reg)
    const int gw = w0 + col;
    if (gw < WID) {
        #pragma unroll
        for (int pg = 0; pg < 2; ++pg) {
            const int py = phalf*2 + pg;
            #pragma unroll
            for (int og = 0; og < 2; ++og) {
                #pragma unroll
                for (int r = 0; r < 4; ++r) {
                    int o = o0 + ohalf*32 + og*16 + kg*4 + r;
                    float vr = acc[pg][og][r] + bo[o];
                    out[((size_t)bt*CCH + o)*HWP + (size_t)(h0 + py)*WID + gw] =
                        (vr >= 0.f) ? vr : 0.2f*vr;
                }
            }
        }
    }
}

extern "C" void kernel_launch(void* const* d_in, const int* in_sizes, int n_in,
                              void* d_out, int out_size, void* d_ws, size_t ws_size,
                              hipStream_t stream)
{
    const float* x  = (const float*)d_in[0];
    const float* m  = (const float*)d_in[1];
    const float* Wq = (const float*)d_in[2];
    const float* bq = (const float*)d_in[3];
    const float* Wk = (const float*)d_in[4];
    const float* bk = (const float*)d_in[5];
    const float* Wv = (const float*)d_in[6];
    const float* bv = (const float*)d_in[7];
    const float* Wo = (const float*)d_in[8];
    const float* bo = (const float*)d_in[9];
    float* out = (float*)d_out;

    char* ws = (char*)d_ws;
    bf16*  Qp = (bf16*) (ws + 0);            // 13,271,040 bf16
    bf16*  Kp = (bf16*) (ws + 26542080);
    bf16*  Vp = (bf16*) (ws + 53084160);
    float* S  = (float*)(ws + 79626240);     // up to 2*2304*2304 fp32
    bf16*  Y  = (bf16*) (ws + 122093568);    // 53,084,160 bf16
    float* MK = (float*)(ws + 228261888);    // 4608 fp32
    bf16*  WB = (bf16*) (ws + 0);            // wprep output; reuses Qp (dead by conv time)

    static const int s_pw[4] = {54,27,18,9};
    static const int s_ph[4] = {30,15,10,5};
    static const int s_oo[4] = {4,8,12,24};   // oh == ow per scale
    static const int s_N[4]  = {64,256,576,2304};
    static const int s_D[4]  = {103680,25920,11520,2880};
    static const int s_sp[4] = {256,64,16,1};

    for (int s = 0; s < 4; ++s) {
        const int pw = s_pw[s], ph = s_ph[s], oo = s_oo[s];
        const int N = s_N[s], D = s_D[s], nsplit = s_sp[s];
        const int c0 = s*64;
        qkv_patch_kernel<<<dim3(405, NBT), 256, 0, stream>>>(
            x, Wq, bq, Wk, bk, Wv, bv, Qp, Kp, Vp, c0, oo, oo, ph, pw, N, D);
        mask_kernel<<<dim3(2*N), 256, 0, stream>>>(m, MK, oo, oo, ph, pw, N);
        const int ztot = 2*N*N;
        zero_kernel<<<dim3((ztot+255)/256), 256, 0, stream>>>(S, ztot);
        scores_kernel<<<dim3(N/64, N/64, 2*nsplit), 256, 0, stream>>>(Qp, Kp, S, N, D, nsplit);
        softmax_kernel<<<dim3(2*N), 256, 0, stream>>>(S, MK, N, 1.0f/sqrtf((float)D));
        pv_kernel<<<dim3(D/64, N/64, 2), 256, 0, stream>>>(S, Vp, Y, N, D, c0, oo, oo, ph, pw);
    }
    wprep_kernel<<<dim3(256), 256, 0, stream>>>(Wo, WB);
    conv_mfma_kernel<<<dim3(14, 30, NBT*4), 256, 0, stream>>>(Y, WB, bo, out);
}

// Round 7
// 3085.029 us; speedup vs baseline: 3.2006x; 1.9808x over previous
//
#include <hip/hip_runtime.h>
#include <hip/hip_bf16.h>
#include <math.h>

typedef __hip_bfloat16 bf16;
typedef __attribute__((ext_vector_type(8))) short short8v;
typedef __attribute__((ext_vector_type(4))) float floatx4;

#define TT 4
#define CCH 256
#define HGT 120
#define WID 216
#define HWP (HGT*WID)   // 25920
#define NBT 8

__device__ __forceinline__ float bfu2f(unsigned short u) {
    union { unsigned int i; float f; } c; c.i = ((unsigned int)u) << 16; return c.f;
}
__device__ __forceinline__ unsigned short f2bu(float f) {
    bf16 h = __float2bfloat16(f);
    return *(unsigned short*)&h;
}
__device__ __forceinline__ short8v lds_load8(const unsigned short* p) {
    short8v r;
    *(uint2*)&r       = *(const uint2*)p;
    *((uint2*)&r + 1) = *(const uint2*)(p + 4);
    return r;
}

// ---------------- weight prep: Wq/Wk/Wv fp32 [och][c] -> bf16 [kind][och][c] ----------
__global__ __launch_bounds__(256)
void wqkv_prep_kernel(const float* __restrict__ Wq, const float* __restrict__ Wk,
                      const float* __restrict__ Wv, unsigned short* __restrict__ wqkv)
{
    int idx = blockIdx.x*256 + threadIdx.x;      // 0..196607
    int kind = idx >> 16;
    int rem = idx & 65535;
    const float* src = (kind == 0) ? Wq : (kind == 1) ? Wk : Wv;
    wqkv[idx] = f2bu(src[rem]);
}

// ---------------- QKV projection via MFMA + patchify write (one 64-ch slice) ----------
// grid (405, 8), block 256 (4 waves). Block: 64 px x 64 och x 3 kinds.
// A = W[och][c], B = x[c][px], C[och][px]. V written transposed: Vt[b][d][n].
__global__ __launch_bounds__(256)
void qkv_mfma_kernel(const float* __restrict__ x, const unsigned short* __restrict__ wqkv,
                     const float* __restrict__ bq, const float* __restrict__ bk,
                     const float* __restrict__ bv,
                     unsigned short* __restrict__ Qp, unsigned short* __restrict__ Kp,
                     unsigned short* __restrict__ Vt,
                     int c0, int oh, int ow, int ph, int pw, int N, int D)
{
    __shared__ unsigned short xs[64*36];     // [px][c]
    __shared__ unsigned short wl[3*64*36];   // [kind][och][c]
    const int tid = threadIdx.x;
    const int bt = blockIdx.y;
    const int p0 = blockIdx.x * 64;
    const int b = bt / TT, t = bt % TT;
    const int lane = tid & 63, wv = tid >> 6;
    const int col = lane & 15, kg = lane >> 4;
    const int phalf = wv & 1, ohalf = wv >> 1;

    floatx4 acc[3][2][2];
    #pragma unroll
    for (int kk = 0; kk < 3; ++kk)
        #pragma unroll
        for (int og = 0; og < 2; ++og)
            #pragma unroll
            for (int pg = 0; pg < 2; ++pg)
                acc[kk][og][pg] = (floatx4){0.f,0.f,0.f,0.f};

    const int spx = tid & 63, scg = tid >> 6;    // xs staging: 64px x 4 c-groups
    const int so = tid >> 2, swg = tid & 3;      // wl staging: 64 och x 4 c-groups

    for (int cb = 0; cb < CCH; cb += 32) {
        __syncthreads();
        {
            const float* xp = x + ((size_t)bt*CCH + cb + scg*8)*HWP + p0 + spx;
            unsigned short tmp[8];
            #pragma unroll
            for (int j = 0; j < 8; ++j) tmp[j] = f2bu(xp[(size_t)j*HWP]);
            uint2* dst = (uint2*)&xs[spx*36 + scg*8];
            dst[0] = make_uint2((unsigned)tmp[0] | ((unsigned)tmp[1]<<16),
                                (unsigned)tmp[2] | ((unsigned)tmp[3]<<16));
            dst[1] = make_uint2((unsigned)tmp[4] | ((unsigned)tmp[5]<<16),
                                (unsigned)tmp[6] | ((unsigned)tmp[7]<<16));
        }
        #pragma unroll
        for (int kk = 0; kk < 3; ++kk) {
            uint4 w4 = *(const uint4*)(wqkv + ((size_t)(kk*256 + c0 + so))*256 + cb + swg*8);
            uint2* dst = (uint2*)&wl[kk*2304 + so*36 + swg*8];
            dst[0] = make_uint2(w4.x, w4.y);
            dst[1] = make_uint2(w4.z, w4.w);
        }
        __syncthreads();
        short8v bx[2];
        #pragma unroll
        for (int pg = 0; pg < 2; ++pg)
            bx[pg] = lds_load8(&xs[(phalf*32 + pg*16 + col)*36 + kg*8]);
        #pragma unroll
        for (int kk = 0; kk < 3; ++kk) {
            #pragma unroll
            for (int og = 0; og < 2; ++og) {
                short8v aw = lds_load8(&wl[kk*2304 + (ohalf*32 + og*16 + col)*36 + kg*8]);
                #pragma unroll
                for (int pg = 0; pg < 2; ++pg)
                    acc[kk][og][pg] = __builtin_amdgcn_mfma_f32_16x16x32_bf16(
                        aw, bx[pg], acc[kk][og][pg], 0, 0, 0);
            }
        }
    }

    const int phpw = ph*pw;
    #pragma unroll
    for (int pg = 0; pg < 2; ++pg) {
        const int p = p0 + phalf*32 + pg*16 + col;
        const int h = p / WID, w = p - h*WID;
        const int ohi = h / ph, py = h - ohi*ph;
        const int owi = w / pw, pxx = w - owi*pw;
        const int n = (t*oh + ohi)*ow + owi;
        const int doff = py*pw + pxx;
        const size_t rbase = ((size_t)b*N + n)*(size_t)D;
        #pragma unroll
        for (int og = 0; og < 2; ++og) {
            #pragma unroll
            for (int r = 0; r < 4; ++r) {
                const int ck = ohalf*32 + og*16 + kg*4 + r;
                const int d = ck*phpw + doff;
                Qp[rbase + d] = f2bu(acc[0][og][pg][r] + bq[c0+ck]);
                Kp[rbase + d] = f2bu(acc[1][og][pg][r] + bk[c0+ck]);
                Vt[((size_t)b*D + d)*N + n] = f2bu(acc[2][og][pg][r] + bv[c0+ck]);
            }
        }
    }
}

// ---------------- per-patch mask means -------------
__global__ __launch_bounds__(256)
void mask_kernel(const float* __restrict__ m, float* __restrict__ maskf,
                 int oh, int ow, int ph, int pw, int N)
{
    const int bn = blockIdx.x;
    const int b = bn / N, n = bn % N;
    const int ohow = oh*ow;
    const int t = n / ohow, r = n % ohow;
    const int ohi = r / ow, owi = r % ow;
    const float* mp = m + (size_t)(b*TT + t)*HWP;
    const int cnt = ph*pw;
    double s = 0.0;
    for (int i = threadIdx.x; i < cnt; i += 256) {
        int py = i / pw, px = i % pw;
        s += (double)mp[(size_t)(ohi*ph + py)*WID + owi*pw + px];
    }
    __shared__ double red[4];
    #pragma unroll
    for (int off = 32; off > 0; off >>= 1) s += __shfl_down(s, off);
    if ((threadIdx.x & 63) == 0) red[threadIdx.x >> 6] = s;
    __syncthreads();
    if (threadIdx.x == 0) {
        double tot = red[0]+red[1]+red[2]+red[3];
        maskf[bn] = (tot > 0.5*(double)cnt) ? 1.0f : 0.0f;
    }
}

__global__ void zero_kernel(float* __restrict__ p, int n) {
    int i = blockIdx.x*256 + threadIdx.x;
    if (i < n) p[i] = 0.f;
}

// ---------------- scores = Qp·Kp^T via MFMA (split-K, fp32 atomic accumulate) ---------
// grid (N/64, N/64, 2*nsplit), block 256 (4 waves). Wave: 32n x 32m.
__global__ __launch_bounds__(256)
void scores_mfma_kernel(const unsigned short* __restrict__ Qp,
                        const unsigned short* __restrict__ Kp,
                        float* __restrict__ S, int N, int D, int nsplit)
{
    __shared__ unsigned short qs[64*36], ks[64*36];   // [token][k]
    const int tid = threadIdx.x;
    const int b = blockIdx.z / nsplit, sp = blockIdx.z % nsplit;
    const int kchunks = D >> 5;
    const int per = (kchunks + nsplit - 1) / nsplit;
    const int k0 = sp*per*32;
    const int k1 = min(D, k0 + per*32);
    const unsigned short* Qb = Qp + (size_t)b*N*D;
    const unsigned short* Kb = Kp + (size_t)b*N*D;
    const int n0 = blockIdx.y*64, m0 = blockIdx.x*64;
    const int lane = tid & 63, wv = tid >> 6;
    const int col = lane & 15, kg = lane >> 4;
    const int nhalf = wv & 1, mhalf = wv >> 1;
    const int stok = tid >> 2, sgg = tid & 3;

    floatx4 acc[2][2];
    #pragma unroll
    for (int i = 0; i < 2; ++i)
        #pragma unroll
        for (int j = 0; j < 2; ++j) acc[i][j] = (floatx4){0.f,0.f,0.f,0.f};

    for (int kb = k0; kb < k1; kb += 32) {
        __syncthreads();
        {
            uint4 q4 = *(const uint4*)(Qb + (size_t)(n0+stok)*D + kb + sgg*8);
            uint2* qd = (uint2*)&qs[stok*36 + sgg*8];
            qd[0] = make_uint2(q4.x, q4.y); qd[1] = make_uint2(q4.z, q4.w);
            uint4 k4 = *(const uint4*)(Kb + (size_t)(m0+stok)*D + kb + sgg*8);
            uint2* kd = (uint2*)&ks[stok*36 + sgg*8];
            kd[0] = make_uint2(k4.x, k4.y); kd[1] = make_uint2(k4.z, k4.w);
        }
        __syncthreads();
        short8v aq[2], bk2[2];
        #pragma unroll
        for (int i = 0; i < 2; ++i)
            aq[i] = lds_load8(&qs[(nhalf*32 + i*16 + col)*36 + kg*8]);
        #pragma unroll
        for (int j = 0; j < 2; ++j)
            bk2[j] = lds_load8(&ks[(mhalf*32 + j*16 + col)*36 + kg*8]);
        #pragma unroll
        for (int i = 0; i < 2; ++i)
            #pragma unroll
            for (int j = 0; j < 2; ++j)
                acc[i][j] = __builtin_amdgcn_mfma_f32_16x16x32_bf16(
                    aq[i], bk2[j], acc[i][j], 0, 0, 0);
    }
    #pragma unroll
    for (int i = 0; i < 2; ++i) {
        #pragma unroll
        for (int j = 0; j < 2; ++j) {
            #pragma unroll
            for (int r = 0; r < 4; ++r) {
                const int n = n0 + nhalf*32 + i*16 + kg*4 + r;
                const int mm = m0 + mhalf*32 + j*16 + col;
                const size_t a = ((size_t)b*N + n)*N + mm;
                if (nsplit > 1) atomicAdd(&S[a], acc[i][j][r]);
                else            S[a] = acc[i][j][r];
            }
        }
    }
}

// ---------------- masked softmax: S fp32 -> P bf16 -------------
__global__ __launch_bounds__(256)
void softmax_kernel(const float* __restrict__ S, const float* __restrict__ maskf,
                    unsigned short* __restrict__ Pout, int N, float rscale)
{
    __shared__ float buf[2304];
    __shared__ float red[4];
    __shared__ float bval;
    const int tid = threadIdx.x;
    const int bn = blockIdx.x;
    const int b = bn / N;
    const float* rowp = S + (size_t)bn*N;
    const float* mk = maskf + (size_t)b*N;
    float mx = -3.0e38f;
    for (int mc = tid; mc < N; mc += 256) {
        float s = rowp[mc]*rscale;
        if (mk[mc] > 0.5f) s = -1e9f;
        buf[mc] = s;
        mx = fmaxf(mx, s);
    }
    #pragma unroll
    for (int off = 32; off > 0; off >>= 1) mx = fmaxf(mx, __shfl_down(mx, off));
    if ((tid & 63) == 0) red[tid >> 6] = mx;
    __syncthreads();
    if (tid == 0) bval = fmaxf(fmaxf(red[0],red[1]), fmaxf(red[2],red[3]));
    __syncthreads();
    const float rm = bval;
    float sum = 0.f;
    for (int mc = tid; mc < N; mc += 256) {
        float e = __expf(buf[mc]-rm);
        buf[mc] = e; sum += e;
    }
    #pragma unroll
    for (int off = 32; off > 0; off >>= 1) sum += __shfl_down(sum, off);
    if ((tid & 63) == 0) red[tid >> 6] = sum;
    __syncthreads();
    if (tid == 0) bval = 1.0f/(red[0]+red[1]+red[2]+red[3]);
    __syncthreads();
    const float inv = bval;
    unsigned short* prow = Pout + (size_t)bn*N;
    for (int mc = tid; mc < N; mc += 256) prow[mc] = f2bu(buf[mc]*inv);
}

// ---------------- yi = P·V via MFMA, un-patchify scatter into y (bf16) -------------
// grid (D/64, N/64, 2), block 256. A = P[n][m] (bf16), B = V^T stored Vt[d][m].
__global__ __launch_bounds__(256)
void pv_mfma_kernel(const unsigned short* __restrict__ Pb, const unsigned short* __restrict__ Vt,
                    unsigned short* __restrict__ y, int N, int D,
                    int c0, int oh, int ow, int ph, int pw)
{
    __shared__ unsigned short ps[64*36], vs[64*36];   // [n][m], [d][m]
    const int tid = threadIdx.x;
    const int b = blockIdx.z;
    const unsigned short* Pbb = Pb + (size_t)b*N*N;
    const unsigned short* Vbb = Vt + (size_t)b*D*N;
    const int n0 = blockIdx.y*64, d0 = blockIdx.x*64;
    const int lane = tid & 63, wv = tid >> 6;
    const int col = lane & 15, kg = lane >> 4;
    const int nhalf = wv & 1, dhalf = wv >> 1;
    const int stok = tid >> 2, sgg = tid & 3;

    floatx4 acc[2][2];
    #pragma unroll
    for (int i = 0; i < 2; ++i)
        #pragma unroll
        for (int j = 0; j < 2; ++j) acc[i][j] = (floatx4){0.f,0.f,0.f,0.f};

    for (int mb = 0; mb < N; mb += 32) {
        __syncthreads();
        {
            uint4 p4 = *(const uint4*)(Pbb + (size_t)(n0+stok)*N + mb + sgg*8);
            uint2* pd = (uint2*)&ps[stok*36 + sgg*8];
            pd[0] = make_uint2(p4.x, p4.y); pd[1] = make_uint2(p4.z, p4.w);
            uint4 v4 = *(const uint4*)(Vbb + (size_t)(d0+stok)*N + mb + sgg*8);
            uint2* vd = (uint2*)&vs[stok*36 + sgg*8];
            vd[0] = make_uint2(v4.x, v4.y); vd[1] = make_uint2(v4.z, v4.w);
        }
        __syncthreads();
        short8v ap[2], bv2[2];
        #pragma unroll
        for (int i = 0; i < 2; ++i)
            ap[i] = lds_load8(&ps[(nhalf*32 + i*16 + col)*36 + kg*8]);
        #pragma unroll
        for (int j = 0; j < 2; ++j)
            bv2[j] = lds_load8(&vs[(dhalf*32 + j*16 + col)*36 + kg*8]);
        #pragma unroll
        for (int i = 0; i < 2; ++i)
            #pragma unroll
            for (int j = 0; j < 2; ++j)
                acc[i][j] = __builtin_amdgcn_mfma_f32_16x16x32_bf16(
                    ap[i], bv2[j], acc[i][j], 0, 0, 0);
    }

    const int ohow = oh*ow, phpw = ph*pw;
    #pragma unroll
    for (int j = 0; j < 2; ++j) {
        const int d = d0 + dhalf*32 + j*16 + col;
        const int ck = d / phpw, r2 = d - ck*phpw;
        const int py = r2 / pw, pxx = r2 - py*pw;
        #pragma unroll
        for (int i = 0; i < 2; ++i) {
            #pragma unroll
            for (int r = 0; r < 4; ++r) {
                const int n = n0 + nhalf*32 + i*16 + kg*4 + r;
                const int t = n / ohow, rn = n - t*ohow;
                const int ohi = rn / ow, owi = rn - ohi*ow;
                y[((size_t)(b*TT + t)*CCH + c0 + ck)*HWP +
                  (size_t)(ohi*ph + py)*WID + owi*pw + pxx] = f2bu(acc[i][j][r]);
            }
        }
    }
}

// ---------------- weight prep: Wo fp32 [o][c][3][3] -> bf16 [off][o][c] -------------
__global__ __launch_bounds__(256)
void wprep_kernel(const float* __restrict__ Wo, bf16* __restrict__ wbf)
{
    int i = blockIdx.x*256 + threadIdx.x;   // 65536 threads: o = i>>8, c = i&255
    int o = i >> 8, c = i & 255;
    const float* src = Wo + (size_t)(o*256 + c)*9;
    #pragma unroll
    for (int off = 0; off < 9; ++off)
        wbf[(size_t)(off*256 + o)*256 + c] = __float2bfloat16(src[off]);
}

// ---------------- 3x3 conv + bias + LeakyReLU via MFMA implicit GEMM -------------
// grid (14, 30, 8*4), block 256 (4 waves). Block tile: 4h x 16w pixels, 64 out ch.
__global__ __launch_bounds__(256)
void conv_mfma_kernel(const bf16* __restrict__ y, const bf16* __restrict__ wbf,
                      const float* __restrict__ bo, float* __restrict__ out)
{
    __shared__ unsigned short ys[108*36];    // [pos=ry*18+rx][c]
    __shared__ unsigned short wl[9*64*36];   // [off][o][c]
    const int tid = threadIdx.x;
    const int bz = blockIdx.z;
    const int bt = bz >> 2, o0 = (bz & 3) * 64;
    const int w0 = blockIdx.x * 16, h0 = blockIdx.y * 4;
    const int lane = tid & 63, wv = tid >> 6;
    const int col = lane & 15, kg = lane >> 4;
    const int phalf = wv & 1, ohalf = wv >> 1;

    floatx4 acc[2][2];
    #pragma unroll
    for (int pg = 0; pg < 2; ++pg)
        #pragma unroll
        for (int og = 0; og < 2; ++og)
            acc[pg][og] = (floatx4){0.f, 0.f, 0.f, 0.f};

    const unsigned short* yu = (const unsigned short*)y;
    const unsigned short* wu = (const unsigned short*)wbf;
    const int so = tid >> 2, scg = tid & 3;

    for (int cb = 0; cb < CCH; cb += 32) {
        __syncthreads();
        for (int i = tid; i < 3456; i += 256) {
            int c = i / 108, pos = i - c*108;
            int ry = pos / 18, rx = pos - ry*18;
            int gh = h0 - 1 + ry, gw = w0 - 1 + rx;
            unsigned short v = 0;
            if (gh >= 0 && gh < HGT && gw >= 0 && gw < WID)
                v = yu[((size_t)bt*CCH + cb + c)*HWP + (size_t)gh*WID + gw];
            ys[pos*36 + c] = v;
        }
        #pragma unroll
        for (int off = 0; off < 9; ++off) {
            uint4 w4 = *(const uint4*)(wu + ((size_t)(off*256 + o0 + so)*256 + cb + scg*8));
            uint2* dst = (uint2*)&wl[off*2304 + so*36 + scg*8];
            dst[0] = make_uint2(w4.x, w4.y);
            dst[1] = make_uint2(w4.z, w4.w);
        }
        __syncthreads();
        #pragma unroll
        for (int off = 0; off < 9; ++off) {
            const int ky = off / 3, kx = off - ky*3;
            short8v aw[2], by[2];
            #pragma unroll
            for (int og = 0; og < 2; ++og)
                aw[og] = lds_load8(&wl[off*2304 + (ohalf*32 + og*16 + col)*36 + kg*8]);
            #pragma unroll
            for (int pg = 0; pg < 2; ++pg) {
                const int py = phalf*2 + pg;
                by[pg] = lds_load8(&ys[((py + ky)*18 + col + kx)*36 + kg*8]);
            }
            #pragma unroll
            for (int pg = 0; pg < 2; ++pg)
                #pragma unroll
                for (int og = 0; og < 2; ++og)
                    acc[pg][og] = __builtin_amdgcn_mfma_f32_16x16x32_bf16(
                        aw[og], by[pg], acc[pg][og], 0, 0, 0);
        }
    }

    const int gw = w0 + col;
    if (gw < WID) {
        #pragma unroll
        for (int pg = 0; pg < 2; ++pg) {
            const int py = phalf*2 + pg;
            #pragma unroll
            for (int og = 0; og < 2; ++og) {
                #pragma unroll
                for (int r = 0; r < 4; ++r) {
                    int o = o0 + ohalf*32 + og*16 + kg*4 + r;
                    float vr = acc[pg][og][r] + bo[o];
                    out[((size_t)bt*CCH + o)*HWP + (size_t)(h0 + py)*WID + gw] =
                        (vr >= 0.f) ? vr : 0.2f*vr;
                }
            }
        }
    }
}

extern "C" void kernel_launch(void* const* d_in, const int* in_sizes, int n_in,
                              void* d_out, int out_size, void* d_ws, size_t ws_size,
                              hipStream_t stream)
{
    const float* x  = (const float*)d_in[0];
    const float* m  = (const float*)d_in[1];
    const float* Wq = (const float*)d_in[2];
    const float* bq = (const float*)d_in[3];
    const float* Wk = (const float*)d_in[4];
    const float* bk = (const float*)d_in[5];
    const float* Wv = (const float*)d_in[6];
    const float* bv = (const float*)d_in[7];
    const float* Wo = (const float*)d_in[8];
    const float* bo = (const float*)d_in[9];
    float* out = (float*)d_out;

    char* ws = (char*)d_ws;
    unsigned short* Qp = (unsigned short*)(ws + 0);          // 13,271,040 bf16
    unsigned short* Kp = (unsigned short*)(ws + 26542080);
    unsigned short* Vt = (unsigned short*)(ws + 53084160);   // transposed [b][D][N]
    float* S  = (float*)(ws + 79626240);                     // up to 2*2304*2304 fp32
    bf16*  Y  = (bf16*) (ws + 122093568);                    // 53,084,160 bf16
    float* MK = (float*)(ws + 228261888);                    // 4608 fp32
    unsigned short* WQKV = (unsigned short*)(ws + 228280320);// 196,608 bf16
    unsigned short* Pb16 = Qp;                               // alias: Qp dead after scores
    bf16*  WB = (bf16*)(ws + 0);                             // alias: wprep after last pv

    static const int s_pw[4] = {54,27,18,9};
    static const int s_ph[4] = {30,15,10,5};
    static const int s_oo[4] = {4,8,12,24};
    static const int s_N[4]  = {64,256,576,2304};
    static const int s_D[4]  = {103680,25920,11520,2880};
    static const int s_sp[4] = {256,64,16,1};

    wqkv_prep_kernel<<<dim3(768), 256, 0, stream>>>(Wq, Wk, Wv, WQKV);

    for (int s = 0; s < 4; ++s) {
        const int pw = s_pw[s], ph = s_ph[s], oo = s_oo[s];
        const int N = s_N[s], D = s_D[s], nsplit = s_sp[s];
        const int c0 = s*64;
        qkv_mfma_kernel<<<dim3(405, NBT), 256, 0, stream>>>(
            x, WQKV, bq, bk, bv, Qp, Kp, Vt, c0, oo, oo, ph, pw, N, D);
        mask_kernel<<<dim3(2*N), 256, 0, stream>>>(m, MK, oo, oo, ph, pw, N);
        if (nsplit > 1) {
            const int ztot = 2*N*N;
            zero_kernel<<<dim3((ztot+255)/256), 256, 0, stream>>>(S, ztot);
        }
        scores_mfma_kernel<<<dim3(N/64, N/64, 2*nsplit), 256, 0, stream>>>(Qp, Kp, S, N, D, nsplit);
        softmax_kernel<<<dim3(2*N), 256, 0, stream>>>(S, MK, Pb16, N, 1.0f/sqrtf((float)D));
        pv_mfma_kernel<<<dim3(D/64, N/64, 2), 256, 0, stream>>>(
            Pb16, Vt, (unsigned short*)Y, N, D, c0, oo, oo, ph, pw);
    }
    wprep_kernel<<<dim3(256), 256, 0, stream>>>(Wo, WB);
    conv_mfma_kernel<<<dim3(14, 30, NBT*4), 256, 0, stream>>>(Y, WB, bo, out);
}

// Round 10
// 2791.719 us; speedup vs baseline: 3.5368x; 1.1051x over previous
//
#include <hip/hip_runtime.h>
#include <hip/hip_bf16.h>
#include <math.h>

typedef __hip_bfloat16 bf16;
typedef __attribute__((ext_vector_type(8))) short short8v;
typedef __attribute__((ext_vector_type(4))) float floatx4;

#define TT 4
#define CCH 256
#define HGT 120
#define WID 216
#define HWP (HGT*WID)   // 25920
#define NBT 8

__device__ __forceinline__ float bfu2f(unsigned short u) {
    union { unsigned int i; float f; } c; c.i = ((unsigned int)u) << 16; return c.f;
}
__device__ __forceinline__ unsigned short f2bu(float f) {
    bf16 h = __float2bfloat16(f);
    return *(unsigned short*)&h;
}
__device__ __forceinline__ short8v lds_load8(const unsigned short* p) {
    short8v r;
    *(uint2*)&r       = *(const uint2*)p;
    *((uint2*)&r + 1) = *(const uint2*)(p + 4);
    return r;
}

// ---------------- weight prep: Wq/Wk/Wv fp32 [och][c] -> bf16 [kind][och][c] ----------
__global__ __launch_bounds__(256)
void wqkv_prep_kernel(const float* __restrict__ Wq, const float* __restrict__ Wk,
                      const float* __restrict__ Wv, unsigned short* __restrict__ wqkv)
{
    int idx = blockIdx.x*256 + threadIdx.x;      // 0..196607
    int kind = idx >> 16;
    int rem = idx & 65535;
    const float* src = (kind == 0) ? Wq : (kind == 1) ? Wk : Wv;
    wqkv[idx] = f2bu(src[rem]);
}

// ---------------- QKV projection via MFMA + patchify write (one 64-ch slice) ----------
// grid (405, 8), block 256 (4 waves). Block: 64 px x 64 och x 3 kinds.
__global__ __launch_bounds__(256)
void qkv_mfma_kernel(const float* __restrict__ x, const unsigned short* __restrict__ wqkv,
                     const float* __restrict__ bq, const float* __restrict__ bk,
                     const float* __restrict__ bv,
                     unsigned short* __restrict__ Qp, unsigned short* __restrict__ Kp,
                     unsigned short* __restrict__ Vt,
                     int c0, int oh, int ow, int ph, int pw, int N, int D)
{
    __shared__ unsigned short xs[64*36];     // [px][c]
    __shared__ unsigned short wl[3*64*36];   // [kind][och][c]
    const int tid = threadIdx.x;
    const int bt = blockIdx.y;
    const int p0 = blockIdx.x * 64;
    const int b = bt / TT, t = bt % TT;
    const int lane = tid & 63, wv = tid >> 6;
    const int col = lane & 15, kg = lane >> 4;
    const int phalf = wv & 1, ohalf = wv >> 1;

    floatx4 acc[3][2][2];
    #pragma unroll
    for (int kk = 0; kk < 3; ++kk)
        #pragma unroll
        for (int og = 0; og < 2; ++og)
            #pragma unroll
            for (int pg = 0; pg < 2; ++pg)
                acc[kk][og][pg] = (floatx4){0.f,0.f,0.f,0.f};

    const int spx = tid & 63, scg = tid >> 6;    // xs staging: 64px x 4 c-groups
    const int so = tid >> 2, swg = tid & 3;      // wl staging: 64 och x 4 c-groups

    for (int cb = 0; cb < CCH; cb += 32) {
        __syncthreads();
        {
            const float* xp = x + ((size_t)bt*CCH + cb + scg*8)*HWP + p0 + spx;
            unsigned short tmp[8];
            #pragma unroll
            for (int j = 0; j < 8; ++j) tmp[j] = f2bu(xp[(size_t)j*HWP]);
            uint2* dst = (uint2*)&xs[spx*36 + scg*8];
            dst[0] = make_uint2((unsigned)tmp[0] | ((unsigned)tmp[1]<<16),
                                (unsigned)tmp[2] | ((unsigned)tmp[3]<<16));
            dst[1] = make_uint2((unsigned)tmp[4] | ((unsigned)tmp[5]<<16),
                                (unsigned)tmp[6] | ((unsigned)tmp[7]<<16));
        }
        #pragma unroll
        for (int kk = 0; kk < 3; ++kk) {
            uint4 w4 = *(const uint4*)(wqkv + ((size_t)(kk*256 + c0 + so))*256 + cb + swg*8);
            uint2* dst = (uint2*)&wl[kk*2304 + so*36 + swg*8];
            dst[0] = make_uint2(w4.x, w4.y);
            dst[1] = make_uint2(w4.z, w4.w);
        }
        __syncthreads();
        short8v bx[2];
        #pragma unroll
        for (int pg = 0; pg < 2; ++pg)
            bx[pg] = lds_load8(&xs[(phalf*32 + pg*16 + col)*36 + kg*8]);
        #pragma unroll
        for (int kk = 0; kk < 3; ++kk) {
            #pragma unroll
            for (int og = 0; og < 2; ++og) {
                short8v aw = lds_load8(&wl[kk*2304 + (ohalf*32 + og*16 + col)*36 + kg*8]);
                #pragma unroll
                for (int pg = 0; pg < 2; ++pg)
                    acc[kk][og][pg] = __builtin_amdgcn_mfma_f32_16x16x32_bf16(
                        aw, bx[pg], acc[kk][og][pg], 0, 0, 0);
            }
        }
    }

    const int phpw = ph*pw;
    #pragma unroll
    for (int pg = 0; pg < 2; ++pg) {
        const int p = p0 + phalf*32 + pg*16 + col;
        const int h = p / WID, w = p - h*WID;
        const int ohi = h / ph, py = h - ohi*ph;
        const int owi = w / pw, pxx = w - owi*pw;
        const int n = (t*oh + ohi)*ow + owi;
        const int doff = py*pw + pxx;
        const size_t rbase = ((size_t)b*N + n)*(size_t)D;
        #pragma unroll
        for (int og = 0; og < 2; ++og) {
            #pragma unroll
            for (int r = 0; r < 4; ++r) {
                const int ck = ohalf*32 + og*16 + kg*4 + r;
                const int d = ck*phpw + doff;
                Qp[rbase + d] = f2bu(acc[0][og][pg][r] + bq[c0+ck]);
                Kp[rbase + d] = f2bu(acc[1][og][pg][r] + bk[c0+ck]);
                Vt[((size_t)b*D + d)*N + n] = f2bu(acc[2][og][pg][r] + bv[c0+ck]);
            }
        }
    }
}

// ---------------- per-patch mask means -------------
__global__ __launch_bounds__(256)
void mask_kernel(const float* __restrict__ m, float* __restrict__ maskf,
                 int oh, int ow, int ph, int pw, int N)
{
    const int bn = blockIdx.x;
    const int b = bn / N, n = bn % N;
    const int ohow = oh*ow;
    const int t = n / ohow, r = n % ohow;
    const int ohi = r / ow, owi = r % ow;
    const float* mp = m + (size_t)(b*TT + t)*HWP;
    const int cnt = ph*pw;
    double s = 0.0;
    for (int i = threadIdx.x; i < cnt; i += 256) {
        int py = i / pw, px = i % pw;
        s += (double)mp[(size_t)(ohi*ph + py)*WID + owi*pw + px];
    }
    __shared__ double red[4];
    #pragma unroll
    for (int off = 32; off > 0; off >>= 1) s += __shfl_down(s, off);
    if ((threadIdx.x & 63) == 0) red[threadIdx.x >> 6] = s;
    __syncthreads();
    if (threadIdx.x == 0) {
        double tot = red[0]+red[1]+red[2]+red[3];
        maskf[bn] = (tot > 0.5*(double)cnt) ? 1.0f : 0.0f;
    }
}

__global__ void zero_kernel(float* __restrict__ p, int n) {
    int i = blockIdx.x*256 + threadIdx.x;
    if (i < n) p[i] = 0.f;
}

// ---------------- scores = Qp·Kp^T via MFMA (split-K, fp32 atomic accumulate) ---------
__global__ __launch_bounds__(256)
void scores_mfma_kernel(const unsigned short* __restrict__ Qp,
                        const unsigned short* __restrict__ Kp,
                        float* __restrict__ S, int N, int D, int nsplit)
{
    __shared__ unsigned short qs[64*36], ks[64*36];   // [token][k]
    const int tid = threadIdx.x;
    const int b = blockIdx.z / nsplit, sp = blockIdx.z % nsplit;
    const int kchunks = D >> 5;
    const int per = (kchunks + nsplit - 1) / nsplit;
    const int k0 = sp*per*32;
    const int k1 = min(D, k0 + per*32);
    const unsigned short* Qb = Qp + (size_t)b*N*D;
    const unsigned short* Kb = Kp + (size_t)b*N*D;
    const int n0 = blockIdx.y*64, m0 = blockIdx.x*64;
    const int lane = tid & 63, wv = tid >> 6;
    const int col = lane & 15, kg = lane >> 4;
    const int nhalf = wv & 1, mhalf = wv >> 1;
    const int stok = tid >> 2, sgg = tid & 3;

    floatx4 acc[2][2];
    #pragma unroll
    for (int i = 0; i < 2; ++i)
        #pragma unroll
        for (int j = 0; j < 2; ++j) acc[i][j] = (floatx4){0.f,0.f,0.f,0.f};

    for (int kb = k0; kb < k1; kb += 32) {
        __syncthreads();
        {
            uint4 q4 = *(const uint4*)(Qb + (size_t)(n0+stok)*D + kb + sgg*8);
            uint2* qd = (uint2*)&qs[stok*36 + sgg*8];
            qd[0] = make_uint2(q4.x, q4.y); qd[1] = make_uint2(q4.z, q4.w);
            uint4 k4 = *(const uint4*)(Kb + (size_t)(m0+stok)*D + kb + sgg*8);
            uint2* kd = (uint2*)&ks[stok*36 + sgg*8];
            kd[0] = make_uint2(k4.x, k4.y); kd[1] = make_uint2(k4.z, k4.w);
        }
        __syncthreads();
        short8v aq[2], bk2[2];
        #pragma unroll
        for (int i = 0; i < 2; ++i)
            aq[i] = lds_load8(&qs[(nhalf*32 + i*16 + col)*36 + kg*8]);
        #pragma unroll
        for (int j = 0; j < 2; ++j)
            bk2[j] = lds_load8(&ks[(mhalf*32 + j*16 + col)*36 + kg*8]);
        #pragma unroll
        for (int i = 0; i < 2; ++i)
            #pragma unroll
            for (int j = 0; j < 2; ++j)
                acc[i][j] = __builtin_amdgcn_mfma_f32_16x16x32_bf16(
                    aq[i], bk2[j], acc[i][j], 0, 0, 0);
    }
    #pragma unroll
    for (int i = 0; i < 2; ++i) {
        #pragma unroll
        for (int j = 0; j < 2; ++j) {
            #pragma unroll
            for (int r = 0; r < 4; ++r) {
                const int n = n0 + nhalf*32 + i*16 + kg*4 + r;
                const int mm = m0 + mhalf*32 + j*16 + col;
                const size_t a = ((size_t)b*N + n)*N + mm;
                if (nsplit > 1) atomicAdd(&S[a], acc[i][j][r]);
                else            S[a] = acc[i][j][r];
            }
        }
    }
}

// ---------------- masked softmax: S fp32 -> P bf16 -------------
__global__ __launch_bounds__(256)
void softmax_kernel(const float* __restrict__ S, const float* __restrict__ maskf,
                    unsigned short* __restrict__ Pout, int N, float rscale)
{
    __shared__ float buf[2304];
    __shared__ float red[4];
    __shared__ float bval;
    const int tid = threadIdx.x;
    const int bn = blockIdx.x;
    const int b = bn / N;
    const float* rowp = S + (size_t)bn*N;
    const float* mk = maskf + (size_t)b*N;
    float mx = -3.0e38f;
    for (int mc = tid; mc < N; mc += 256) {
        float s = rowp[mc]*rscale;
        if (mk[mc] > 0.5f) s = -1e9f;
        buf[mc] = s;
        mx = fmaxf(mx, s);
    }
    #pragma unroll
    for (int off = 32; off > 0; off >>= 1) mx = fmaxf(mx, __shfl_down(mx, off));
    if ((tid & 63) == 0) red[tid >> 6] = mx;
    __syncthreads();
    if (tid == 0) bval = fmaxf(fmaxf(red[0],red[1]), fmaxf(red[2],red[3]));
    __syncthreads();
    const float rm = bval;
    float sum = 0.f;
    for (int mc = tid; mc < N; mc += 256) {
        float e = __expf(buf[mc]-rm);
        buf[mc] = e; sum += e;
    }
    #pragma unroll
    for (int off = 32; off > 0; off >>= 1) sum += __shfl_down(sum, off);
    if ((tid & 63) == 0) red[tid >> 6] = sum;
    __syncthreads();
    if (tid == 0) bval = 1.0f/(red[0]+red[1]+red[2]+red[3]);
    __syncthreads();
    const float inv = bval;
    unsigned short* prow = Pout + (size_t)bn*N;
    for (int mc = tid; mc < N; mc += 256) prow[mc] = f2bu(buf[mc]*inv);
}

// ---------------- yi = P·V via MFMA, scatter into Y2 [bt][h][w][c] (bf16) ------------
__global__ __launch_bounds__(256)
void pv_mfma_kernel(const unsigned short* __restrict__ Pb, const unsigned short* __restrict__ Vt,
                    unsigned short* __restrict__ y2, int N, int D,
                    int c0, int oh, int ow, int ph, int pw)
{
    __shared__ unsigned short ps[64*36], vs[64*36];   // [n][m], [d][m]
    const int tid = threadIdx.x;
    const int b = blockIdx.z;
    const unsigned short* Pbb = Pb + (size_t)b*N*N;
    const unsigned short* Vbb = Vt + (size_t)b*D*N;
    const int n0 = blockIdx.y*64, d0 = blockIdx.x*64;
    const int lane = tid & 63, wv = tid >> 6;
    const int col = lane & 15, kg = lane >> 4;
    const int nhalf = wv & 1, dhalf = wv >> 1;
    const int stok = tid >> 2, sgg = tid & 3;

    floatx4 acc[2][2];
    #pragma unroll
    for (int i = 0; i < 2; ++i)
        #pragma unroll
        for (int j = 0; j < 2; ++j) acc[i][j] = (floatx4){0.f,0.f,0.f,0.f};

    for (int mb = 0; mb < N; mb += 32) {
        __syncthreads();
        {
            uint4 p4 = *(const uint4*)(Pbb + (size_t)(n0+stok)*N + mb + sgg*8);
            uint2* pd = (uint2*)&ps[stok*36 + sgg*8];
            pd[0] = make_uint2(p4.x, p4.y); pd[1] = make_uint2(p4.z, p4.w);
            uint4 v4 = *(const uint4*)(Vbb + (size_t)(d0+stok)*N + mb + sgg*8);
            uint2* vd = (uint2*)&vs[stok*36 + sgg*8];
            vd[0] = make_uint2(v4.x, v4.y); vd[1] = make_uint2(v4.z, v4.w);
        }
        __syncthreads();
        short8v ap[2], bv2[2];
        #pragma unroll
        for (int i = 0; i < 2; ++i)
            ap[i] = lds_load8(&ps[(nhalf*32 + i*16 + col)*36 + kg*8]);
        #pragma unroll
        for (int j = 0; j < 2; ++j)
            bv2[j] = lds_load8(&vs[(dhalf*32 + j*16 + col)*36 + kg*8]);
        #pragma unroll
        for (int i = 0; i < 2; ++i)
            #pragma unroll
            for (int j = 0; j < 2; ++j)
                acc[i][j] = __builtin_amdgcn_mfma_f32_16x16x32_bf16(
                    ap[i], bv2[j], acc[i][j], 0, 0, 0);
    }

    const int ohow = oh*ow, phpw = ph*pw;
    #pragma unroll
    for (int j = 0; j < 2; ++j) {
        const int d = d0 + dhalf*32 + j*16 + col;
        const int ck = d / phpw, r2 = d - ck*phpw;
        const int py = r2 / pw, pxx = r2 - py*pw;
        #pragma unroll
        for (int i = 0; i < 2; ++i) {
            #pragma unroll
            for (int r = 0; r < 4; ++r) {
                const int n = n0 + nhalf*32 + i*16 + kg*4 + r;
                const int t = n / ohow, rn = n - t*ohow;
                const int ohi = rn / ow, owi = rn - ohi*ow;
                // Y2 layout: [bt][h][w][c]
                y2[((size_t)(b*TT + t)*HWP + (size_t)(ohi*ph + py)*WID + owi*pw + pxx)*CCH
                   + c0 + ck] = f2bu(acc[i][j][r]);
            }
        }
    }
}

// ---------------- weight prep: Wo fp32 [o][c][3][3] -> bf16 [off][o][c] -------------
__global__ __launch_bounds__(256)
void wprep_kernel(const float* __restrict__ Wo, bf16* __restrict__ wbf)
{
    int i = blockIdx.x*256 + threadIdx.x;   // 65536 threads: o = i>>8, c = i&255
    int o = i >> 8, c = i & 255;
    const float* src = Wo + (size_t)(o*256 + c)*9;
    #pragma unroll
    for (int off = 0; off < 9; ++off)
        wbf[(size_t)(off*256 + o)*256 + c] = __float2bfloat16(src[off]);
}

// ---------------- 3x3 conv + bias + LeakyReLU via MFMA implicit GEMM (v2) ------------
// grid (7, 15, 8*4), block 256 (4 waves). Block tile: 8h x 32w px, 64 out ch.
// Y2 input [bt][h][w][c] -> vectorized halo staging, no transpose.
// Wave tile 64px x 64o: per offset 8 ds_read_b128 feed 16 MFMA.
__global__ __launch_bounds__(256)
void conv_mfma_kernel(const unsigned short* __restrict__ y2, const bf16* __restrict__ wbf,
                      const float* __restrict__ bo, float* __restrict__ out)
{
    __shared__ unsigned short ys[340*36];    // [pos=ry*34+rx][c], 10x34 halo
    __shared__ unsigned short wl[9*64*36];   // [off][o][c]
    const int tid = threadIdx.x;
    const int bz = blockIdx.z;
    const int bt = bz >> 2, o0 = (bz & 3) * 64;
    const int w0 = blockIdx.x * 32, h0 = blockIdx.y * 8;
    const int lane = tid & 63, wv = tid >> 6;
    const int col = lane & 15, kg = lane >> 4;
    const int py0 = wv * 2;                  // each wave: 2 pixel-rows of 32

    floatx4 acc[4][4];                       // [pg][og]
    #pragma unroll
    for (int pg = 0; pg < 4; ++pg)
        #pragma unroll
        for (int og = 0; og < 4; ++og)
            acc[pg][og] = (floatx4){0.f, 0.f, 0.f, 0.f};

    const unsigned short* wu = (const unsigned short*)wbf;
    const int so = tid >> 2, swg = tid & 3;

    for (int cb = 0; cb < CCH; cb += 32) {
        __syncthreads();
        // stage y halo: 340 pos x 32 c, vectorized uint4 (8c each)
        #pragma unroll
        for (int k = 0; k < 6; ++k) {
            int idx = tid + k*256;
            if (idx < 1360) {
                int pos = idx >> 2, q = idx & 3;
                int ry = pos / 34, rx = pos - ry*34;
                int gh = h0 - 1 + ry, gw = w0 - 1 + rx;
                uint4 v = make_uint4(0,0,0,0);
                if (gh >= 0 && gh < HGT && gw >= 0 && gw < WID)
                    v = *(const uint4*)(y2 + (((size_t)bt*HWP + (size_t)gh*WID + gw)<<8)
                                        + cb + q*8);
                uint2* dst = (uint2*)&ys[pos*36 + q*8];
                dst[0] = make_uint2(v.x, v.y);
                dst[1] = make_uint2(v.z, v.w);
            }
        }
        // stage W: 9 offs x 64 o x 32 c
        #pragma unroll
        for (int off = 0; off < 9; ++off) {
            uint4 w4 = *(const uint4*)(wu + ((size_t)(off*256 + o0 + so)*256 + cb + swg*8));
            uint2* dst = (uint2*)&wl[off*2304 + so*36 + swg*8];
            dst[0] = make_uint2(w4.x, w4.y);
            dst[1] = make_uint2(w4.z, w4.w);
        }
        __syncthreads();
        #pragma unroll
        for (int off = 0; off < 9; ++off) {
            const int ky = off / 3, kx = off - ky*3;
            short8v aw[4], by[4];
            #pragma unroll
            for (int og = 0; og < 4; ++og)
                aw[og] = lds_load8(&wl[off*2304 + (og*16 + col)*36 + kg*8]);
            #pragma unroll
            for (int pg = 0; pg < 4; ++pg) {
                const int ry = py0 + (pg >> 1) + ky;
                const int rx = (pg & 1)*16 + col + kx;
                by[pg] = lds_load8(&ys[(ry*34 + rx)*36 + kg*8]);
            }
            #pragma unroll
            for (int pg = 0; pg < 4; ++pg)
                #pragma unroll
                for (int og = 0; og < 4; ++og)
                    acc[pg][og] = __builtin_amdgcn_mfma_f32_16x16x32_bf16(
                        aw[og], by[pg], acc[pg][og], 0, 0, 0);
        }
    }

    // epilogue: D col = pixel (lane&15), row = o-within-16 (kg*4+r)
    #pragma unroll
    for (int pg = 0; pg < 4; ++pg) {
        const int gh = h0 + py0 + (pg >> 1);
        const int gw = w0 + (pg & 1)*16 + col;
        if (gw < WID) {
            #pragma unroll
            for (int og = 0; og < 4; ++og) {
                #pragma unroll
                for (int r = 0; r < 4; ++r) {
                    int o = o0 + og*16 + kg*4 + r;
                    float vr = acc[pg][og][r] + bo[o];
                    out[((size_t)bt*CCH + o)*HWP + (size_t)gh*WID + gw] =
                        (vr >= 0.f) ? vr : 0.2f*vr;
                }
            }
        }
    }
}

extern "C" void kernel_launch(void* const* d_in, const int* in_sizes, int n_in,
                              void* d_out, int out_size, void* d_ws, size_t ws_size,
                              hipStream_t stream)
{
    const float* x  = (const float*)d_in[0];
    const float* m  = (const float*)d_in[1];
    const float* Wq = (const float*)d_in[2];
    const float* bq = (const float*)d_in[3];
    const float* Wk = (const float*)d_in[4];
    const float* bk = (const float*)d_in[5];
    const float* Wv = (const float*)d_in[6];
    const float* bv = (const float*)d_in[7];
    const float* Wo = (const float*)d_in[8];
    const float* bo = (const float*)d_in[9];
    float* out = (float*)d_out;

    char* ws = (char*)d_ws;
    unsigned short* Qp = (unsigned short*)(ws + 0);          // 13,271,040 bf16
    unsigned short* Kp = (unsigned short*)(ws + 26542080);
    unsigned short* Vt = (unsigned short*)(ws + 53084160);   // transposed [b][D][N]
    float* S  = (float*)(ws + 79626240);                     // up to 2*2304*2304 fp32
    unsigned short* Y2 = (unsigned short*)(ws + 122093568);  // [bt][h][w][c] bf16
    float* MK = (float*)(ws + 228261888);                    // 4608 fp32
    unsigned short* WQKV = (unsigned short*)(ws + 228280320);// 196,608 bf16
    unsigned short* Pb16 = Qp;                               // alias: Qp dead after scores
    bf16*  WB = (bf16*)(ws + 0);                             // alias: wprep after last pv

    static const int s_pw[4] = {54,27,18,9};
    static const int s_ph[4] = {30,15,10,5};
    static const int s_oo[4] = {4,8,12,24};
    static const int s_N[4]  = {64,256,576,2304};
    static const int s_D[4]  = {103680,25920,11520,2880};
    static const int s_sp[4] = {256,64,16,1};

    wqkv_prep_kernel<<<dim3(768), 256, 0, stream>>>(Wq, Wk, Wv, WQKV);

    for (int s = 0; s < 4; ++s) {
        const int pw = s_pw[s], ph = s_ph[s], oo = s_oo[s];
        const int N = s_N[s], D = s_D[s], nsplit = s_sp[s];
        const int c0 = s*64;
        qkv_mfma_kernel<<<dim3(405, NBT), 256, 0, stream>>>(
            x, WQKV, bq, bk, bv, Qp, Kp, Vt, c0, oo, oo, ph, pw, N, D);
        mask_kernel<<<dim3(2*N), 256, 0, stream>>>(m, MK, oo, oo, ph, pw, N);
        if (nsplit > 1) {
            const int ztot = 2*N*N;
            zero_kernel<<<dim3((ztot+255)/256), 256, 0, stream>>>(S, ztot);
        }
        scores_mfma_kernel<<<dim3(N/64, N/64, 2*nsplit), 256, 0, stream>>>(Qp, Kp, S, N, D, nsplit);
        softmax_kernel<<<dim3(2*N), 256, 0, stream>>>(S, MK, Pb16, N, 1.0f/sqrtf((float)D));
        pv_mfma_kernel<<<dim3(D/64, N/64, 2), 256, 0, stream>>>(
            Pb16, Vt, Y2, N, D, c0, oo, oo, ph, pw);
    }
    wprep_kernel<<<dim3(256), 256, 0, stream>>>(Wo, WB);
    conv_mfma_kernel<<<dim3(7, 15, NBT*4), 256, 0, stream>>>(Y2, WB, bo, out);
}